// Round 5
// baseline (446.627 us; speedup 1.0000x reference)
//
#include <hip/hip_runtime.h>
#include <stdint.h>
#include <stddef.h>

// Problem constants
#define NB   16
#define NC   64
#define NH   64
#define NW   64
#define KC   16
#define NOUT 64
#define NRANK 8
#define NMLP 32
#define NF   576      // C*3*3
#define NPIX 4096     // H*W
#define XH   66       // halo height/width for channel-last copy
#define NBLK 256      // fused-kernel grid size (== CU count; 1 block/CU by LDS)

typedef short s16x8 __attribute__((ext_vector_type(8)));
typedef short s16x4 __attribute__((ext_vector_type(4)));
typedef float f32x4 __attribute__((ext_vector_type(4)));

__device__ __forceinline__ unsigned short f2bf(float x) {
    union { float f; uint32_t u; } v; v.f = x;
    uint32_t r = v.u + 0x7FFFu + ((v.u >> 16) & 1u);   // RTNE
    return (unsigned short)(r >> 16);
}
__device__ __forceinline__ float bf2f(unsigned short u) {
    union { uint32_t u; float f; } v; v.u = ((uint32_t)u) << 16;
    return v.f;
}

// Device-scope grid barrier. Counter must be pre-zeroed and must not be
// written by anyone until the barrier is globally retired. Counters live in
// out[0..7]: `out` is only written by k_scatter (a later kernel), so no
// clobber-while-spinning is possible.
__device__ __forceinline__ void gbar(int* c) {
    __threadfence();
    __syncthreads();
    if (threadIdx.x == 0) {
        __hip_atomic_fetch_add(c, 1, __ATOMIC_ACQ_REL, __HIP_MEMORY_SCOPE_AGENT);
        while (__hip_atomic_load(c, __ATOMIC_ACQUIRE, __HIP_MEMORY_SCOPE_AGENT) < NBLK)
            __builtin_amdgcn_s_sleep(2);
    }
    __syncthreads();
    __threadfence();
}

// ---------------------------------------------------------------------------
// k_fused: phases A (prep) -> gbar -> B (centers, R0-exact) -> gbar ->
// C (main GEMM, R12 structure as 4 lockstep sub-groups).
// grid 256 x 1024, dynamic LDS 149760 B (max of phase needs; 1 block/CU).
// ---------------------------------------------------------------------------
extern "C" __global__ __launch_bounds__(1024, 1)
void k_fused(const float* __restrict__ x, const int* __restrict__ labels,
             const float* __restrict__ lw1, const float* __restrict__ lb1,
             const float* __restrict__ lw2, const float* __restrict__ lb2,
             const float* __restrict__ lw3, const float* __restrict__ lb3,
             const float* __restrict__ basek,
             const float* __restrict__ bw1, const float* __restrict__ bb1,
             const float* __restrict__ bw2, const float* __restrict__ bb2,
             unsigned short* __restrict__ xcl, unsigned short* __restrict__ basekF,
             unsigned short* __restrict__ lists, unsigned short* __restrict__ slotmap,
             int* __restrict__ counts, float* __restrict__ biasrows,
             unsigned short* __restrict__ wt, unsigned short* __restrict__ outc,
             int* __restrict__ bars)
{
    extern __shared__ __align__(16) char smem[];
    const int tid = threadIdx.x;
    const int st = tid & 255, sg = tid >> 8;      // 4 sub-groups of 256
    const int lane = tid & 63;

    // ================= Phase A: prep (xcl + basekF) =================
    {
        float* tileF = (float*)(smem + sg * 16640);   // 64*65*4 per sub-group
        #pragma unroll 1
        for (int pass = 0; pass < 2; ++pass) {
            const int u = pass * 1024 + sg * 256 + blockIdx.x;
            const bool valid = (u < XH * 16);
            const int b = u & 15, yy = u >> 4;
            const bool interior = valid && (yy > 0) && (yy < XH - 1);
            if (interior) {
                const float* src = x + (size_t)b * NC * (NH * NW) + (yy - 1) * NW;
                #pragma unroll
                for (int rr = 0; rr < 16; ++rr) {
                    int c = rr * 4 + (st >> 6);
                    int xx = st & 63;
                    tileF[c * 65 + xx] = src[(size_t)c * (NH * NW) + xx];
                }
            }
            __syncthreads();
            if (valid) {
                unsigned short* dst = xcl + ((size_t)(b * XH + yy) * XH) * 64;
                if (!interior) {
                    for (int e = st; e < XH * 64; e += 256) dst[e] = 0;
                } else {
                    for (int ee = st; ee < 528; ee += 256) {
                        int xx = ee >> 3;
                        int c0 = (ee & 7) * 8;
                        s16x8 v;
                        #pragma unroll
                        for (int j = 0; j < 8; ++j) {
                            float f = (xx == 0 || xx == XH - 1)
                                          ? 0.f : tileF[(c0 + j) * 65 + (xx - 1)];
                            v[j] = (short)f2bf(f);
                        }
                        *reinterpret_cast<s16x8*>(dst + ee * 8) = v;
                    }
                }
            }
            __syncthreads();
        }
        // basekF: 72 units spread over blocks 0..17 x 4 sub-groups
        const int u2 = blockIdx.x * 4 + sg;
        if (u2 < 72) {
            const int ks = u2 >> 2, wvq = u2 & 3;
            unsigned short outv[16];
            #pragma unroll
            for (int i = 0; i < 16; ++i) {
                int e = st * 16 + i;          // e = r*512 + lane8*8 + j
                int r = e >> 9;
                int lane8 = (e >> 3) & 63;
                int j = e & 7;
                int col = wvq * 16 + (lane8 & 15);
                int fp = (lane8 >> 4) * 8 + ks * 32 + j;
                int tap = fp >> 6, c = fp & 63;
                outv[i] = f2bf(basek[((size_t)r * NF + c * 9 + tap) * NOUT + col]);
            }
            unsigned short* dst = basekF + (size_t)u2 * 4096 + st * 16;
            #pragma unroll
            for (int i = 0; i < 16; ++i) dst[i] = outv[i];
        }
    }
    gbar(&bars[0]);

    // ================= Phase B: centers (R0-exact body) =================
    {
        unsigned short* list = (unsigned short*)smem;          // 8192 B
        int*   wcnt = (int*)(smem + 8192);                     // 64 B
        float* wsum = (float*)(smem + 8256);                   // 36864 B
        float* cbuf = (float*)(smem + 45120);                  // 2304 B
        float* p1   = (float*)(smem + 47424);                  // 8*32*4
        float* pb   = (float*)(smem + 48448);
        float* h1   = (float*)(smem + 49472);
        float* h2   = (float*)(smem + 49600);
        float* hb   = (float*)(smem + 49728);
        float* lrs  = (float*)(smem + 49856);
        const int bk = blockIdx.x;
        const int b = bk & 15, k = bk >> 4;
        const int wv = tid >> 6;                               // 0..15
        const int* lab = labels + b * NPIX;

        // ---- order-preserving compaction (4 iterations)
        int total = 0;
        #pragma unroll 1
        for (int base = 0; base < NPIX; base += 1024) {
            int n = base + tid;
            bool pred = (lab[n] == k);
            unsigned long long m = __ballot(pred);
            if (lane == 0) wcnt[wv] = __popcll(m);
            int pre = __popcll(m & ((1ull << lane) - 1ull));
            __syncthreads();
            int wbase = total;
            for (int i = 0; i < wv; ++i) wbase += wcnt[i];
            int nt = total;
            for (int i = 0; i < 16; ++i) nt += wcnt[i];
            if (pred) {
                int slot = wbase + pre;
                list[slot] = (unsigned short)n;
                slotmap[b * NPIX + n] = (unsigned short)slot;
            }
            total = nt;
            __syncthreads();
        }
        const int cnt = total;
        for (int i = tid; i < cnt; i += 1024) lists[bk * NPIX + i] = list[i];
        if (tid == 0) counts[bk] = cnt;
        __syncthreads();

        // ---- gather: wave wv handles pixels i = wv, wv+16, ...; lane = channel
        float s00 = 0.f, s01 = 0.f, s02 = 0.f,
              s10 = 0.f, s11 = 0.f, s12 = 0.f,
              s20 = 0.f, s21 = 0.f, s22 = 0.f;
        const unsigned short* xb = xcl + (size_t)b * (XH * XH * 64) + lane;
        #pragma unroll 2
        for (int i = wv; i < cnt; i += 16) {
            int n = list[i];
            const unsigned short* p0 = xb + (((n >> 6) * XH) + (n & 63)) * 64;
            s00 += bf2f(p0[0]);
            s01 += bf2f(p0[64]);
            s02 += bf2f(p0[128]);
            const unsigned short* prow1 = p0 + XH * 64;
            s10 += bf2f(prow1[0]);
            s11 += bf2f(prow1[64]);
            s12 += bf2f(prow1[128]);
            const unsigned short* prow2 = p0 + 2 * XH * 64;
            s20 += bf2f(prow2[0]);
            s21 += bf2f(prow2[64]);
            s22 += bf2f(prow2[128]);
        }
        {
            float* wrow = wsum + wv * 576 + lane;
            wrow[0 * 64] = s00; wrow[1 * 64] = s01; wrow[2 * 64] = s02;
            wrow[3 * 64] = s10; wrow[4 * 64] = s11; wrow[5 * 64] = s12;
            wrow[6 * 64] = s20; wrow[7 * 64] = s21; wrow[8 * 64] = s22;
        }
        __syncthreads();

        // ---- reduce 16 waves -> centers (feature order c*9+tap)
        const float inv = 1.f / ((float)cnt + 1e-6f);
        if (tid < NF) {
            int tap = tid >> 6, c = tid & 63;
            float s = 0.f;
            #pragma unroll
            for (int w = 0; w < 16; ++w) s += wsum[w * 576 + tap * 64 + c];
            cbuf[c * 9 + tap] = s * inv;
        }
        __syncthreads();

        // ---- fused MLPs
        if (tid < 256) {
            const int j = tid & 31, ch = tid >> 5;
            float a1 = 0.f, a2 = 0.f;
            for (int i = 0; i < 72; ++i) {
                int f = ch * 72 + i;
                float cv = cbuf[f];
                a1 += cv * lw1[f * NMLP + j];
                a2 += cv * bw1[f * NMLP + j];
            }
            p1[ch * NMLP + j] = a1; pb[ch * NMLP + j] = a2;
        }
        __syncthreads();
        if (tid < NMLP) {
            float a = lb1[tid];
            for (int i = 0; i < 8; ++i) a += p1[i * NMLP + tid];
            h1[tid] = fmaxf(a, 0.f);
        } else if (tid < 2 * NMLP) {
            int j = tid - NMLP;
            float a = bb1[j];
            for (int i = 0; i < 8; ++i) a += pb[i * NMLP + j];
            hb[j] = fmaxf(a, 0.f);
        }
        __syncthreads();
        if (tid < NMLP) {
            float a = lb2[tid];
            for (int i = 0; i < NMLP; ++i) a += h1[i] * lw2[i * NMLP + tid];
            h2[tid] = fmaxf(a, 0.f);
        } else if (tid >= 64 && tid < 128) {
            int o = tid - 64;
            float a = bb2[o];
            for (int i = 0; i < NMLP; ++i) a += hb[i] * bw2[i * NOUT + o];
            biasrows[bk * NOUT + o] = a;
        }
        __syncthreads();
        if (tid < NRANK) {
            float a = lb3[tid];
            for (int i = 0; i < NMLP; ++i) a += h2[i] * lw3[i * NRANK + tid];
            lrs[tid] = a;
        }
        __syncthreads();

        // ---- fused W-expansion: wt[bk][ks][t][8]
        float l8[NRANK];
        #pragma unroll
        for (int r = 0; r < NRANK; ++r) l8[r] = lrs[r];
        unsigned short* wtg = wt + (size_t)bk * (18 * 2048);
        #pragma unroll 2
        for (int q = 0; q < 5; ++q) {
            int m = q * 1024 + tid;            // 0..4607 valid
            if (m < 4608) {
                int ks = m >> 8, t = m & 255;
                const unsigned short* src = basekF
                    + ((size_t)(ks * 4 + (t >> 6)) * 8) * 512 + (t & 63) * 8;
                float w[8] = {0.f, 0.f, 0.f, 0.f, 0.f, 0.f, 0.f, 0.f};
                #pragma unroll
                for (int r = 0; r < NRANK; ++r) {
                    s16x8 bv = *reinterpret_cast<const s16x8*>(src + r * 512);
                    #pragma unroll
                    for (int j = 0; j < 8; ++j)
                        w[j] += l8[r] * bf2f((unsigned short)bv[j]);
                }
                s16x8 f;
                #pragma unroll
                for (int j = 0; j < 8; ++j) f[j] = (short)f2bf(w[j]);
                *reinterpret_cast<s16x8*>(wtg + ks * 2048 + t * 8) = f;
            }
        }
    }
    gbar(&bars[1]);

    // ================= Phase C: main GEMM (R12 structure, 4 sub-groups) ====
    {
        const int bk = blockIdx.x;
        const int b = bk & 15, k = bk >> 4;
        const int wv4 = (tid >> 6) & 3;
        const int quad = lane >> 4, l16 = lane & 15;
        const int cnt = counts[bk];
        int prefix = 0;
        for (int kk = 0; kk < k; ++kk) prefix += counts[kk * 16 + b];

        unsigned short* albuf = (unsigned short*)(smem + sg * 37376);  // 32*584 u16
        float* biasl = (float*)(smem + 4 * 37376);                     // @149504
        if (tid < NOUT) biasl[tid] = biasrows[bk * NOUT + tid];

        const int col = wv4 * 16 + l16;
        const unsigned short* wsrc = wt + (size_t)bk * (18 * 2048) + st * 8;
        s16x8 bfr[18];
        #pragma unroll
        for (int ks = 0; ks < 18; ++ks)
            bfr[ks] = *reinterpret_cast<const s16x8*>(wsrc + ks * 2048);

        const unsigned short* xb = xcl + (size_t)b * (XH * XH * 64);
        const unsigned short* gl = lists + bk * NPIX;
        const int p = st >> 3, part = st & 7;
        const int ntile = (cnt + 31) >> 5;
        const int niter = (ntile + 3) >> 2;
        unsigned short* ob = outc + ((size_t)b * NPIX + prefix) * 64;

        #pragma unroll 1
        for (int it = 0; it < niter; ++it) {
            const int t = it * 4 + sg;
            const bool live = (t < ntile);
            if (live) {
                int slot = (t << 5) + p;
                int n = (slot < cnt) ? (int)gl[slot] : 0;
                const unsigned short* xrow =
                    xb + (((n >> 6) * XH) + (n & 63)) * 64 + part * 8;
                unsigned short* arow = albuf + p * 584 + part * 8;
                #pragma unroll
                for (int tap = 0; tap < 9; ++tap) {
                    int dy = tap / 3, dx = tap - dy * 3;
                    *reinterpret_cast<s16x8*>(arow + tap * 64) =
                        *reinterpret_cast<const s16x8*>(xrow + (dy * XH + dx) * 64);
                }
            }
            __syncthreads();
            if (live) {
                f32x4 acc0 = {0.f, 0.f, 0.f, 0.f}, acc1 = {0.f, 0.f, 0.f, 0.f};
                const unsigned short* ar0 = albuf + l16 * 584 + quad * 8;
                const unsigned short* ar1 = ar0 + 16 * 584;
                #pragma unroll
                for (int ks = 0; ks < 18; ++ks) {
                    s16x8 a0 = *reinterpret_cast<const s16x8*>(ar0 + ks * 32);
                    s16x8 a1 = *reinterpret_cast<const s16x8*>(ar1 + ks * 32);
                    acc0 = __builtin_amdgcn_mfma_f32_16x16x32_bf16(a0, bfr[ks], acc0, 0, 0, 0);
                    acc1 = __builtin_amdgcn_mfma_f32_16x16x32_bf16(a1, bfr[ks], acc1, 0, 0, 0);
                }
                float bb = biasl[col];
                #pragma unroll
                for (int r = 0; r < 4; ++r) {
                    int s0 = (t << 5) + quad * 4 + r;
                    if (s0 < cnt) ob[(size_t)s0 * 64 + col] = f2bf(acc0[r] + bb);
                    int s1 = s0 + 16;
                    if (s1 < cnt) ob[(size_t)s1 * 64 + col] = f2bf(acc1[r] + bb);
                }
            }
            __syncthreads();
        }
    }
}

// ---------------------------------------------------------------------------
// k_scatter (R0 exact): grid 1024. block (b, chunk, q): o-range
// [q*16, q*16+16). 16B gathers, LDS transpose (rows padded to 20 u16),
// coalesced f32 stores. Also overwrites out[0..7] (the barrier counters)
// with real output values.
// ---------------------------------------------------------------------------
extern "C" __global__ __launch_bounds__(256)
void k_scatter(const int* __restrict__ labels, const unsigned short* __restrict__ slotmap,
               const int* __restrict__ counts, const unsigned short* __restrict__ outc,
               float* __restrict__ out)
{
    const int blk = blockIdx.x;
    const int b = blk & 15, chunk = (blk >> 4) & 15, q = blk >> 8;
    const int tid = threadIdx.x;
    __shared__ int pref[KC];
    __shared__ int sptr[256];
    __shared__ unsigned short tt[256 * 20];     // 10 KB
    if (tid < KC) {
        int s = 0;
        for (int kk = 0; kk < tid; ++kk) s += counts[kk * 16 + b];
        pref[tid] = s;
    }
    __syncthreads();
    const int n0 = chunk * 256;
    {
        int n = n0 + tid;
        sptr[tid] = pref[labels[b * NPIX + n]] + (int)slotmap[b * NPIX + n];
    }
    __syncthreads();
    #pragma unroll
    for (int e0 = 0; e0 < 2; ++e0) {
        int e = e0 * 256 + tid;
        int pix = e >> 1, part = e & 1;
        s16x8 vv = *reinterpret_cast<const s16x8*>(
            outc + ((size_t)b * NPIX + sptr[pix]) * 64 + q * 16 + part * 8);
        s16x4 lo = {vv[0], vv[1], vv[2], vv[3]};
        s16x4 hi = {vv[4], vv[5], vv[6], vv[7]};
        *reinterpret_cast<s16x4*>(tt + pix * 20 + part * 8) = lo;
        *reinterpret_cast<s16x4*>(tt + pix * 20 + part * 8 + 4) = hi;
    }
    __syncthreads();
    float* ob = out + ((size_t)(b * NOUT + q * 16)) * NPIX + n0;
    #pragma unroll
    for (int oo = 0; oo < 16; ++oo)
        ob[(size_t)oo * NPIX + tid] = bf2f(tt[tid * 20 + oo]);
}

// ---------------------------------------------------------------------------
// Workspace layout — TOTAL 39,068,672 B (unchanged):
//   lists    @ 0         : 2,097,152
//   counts   @ 2097152   : 1,024
//   biasrows @ 2098176   : 65,536
//   basekF   @ 2163712   : 589,824
//   slotmap  @ 2753536   : 131,072
//   xcl      @ 2884608   : 8,921,088
//   outc     @ 11805696  : 8,388,608
//   wt       @ 20194304  : 18,874,368
// Barrier counters: out[0..7] (zeroed by an 8-B hipMemsetAsync; overwritten
// with real values by k_scatter).
// ---------------------------------------------------------------------------
extern "C" void kernel_launch(void* const* d_in, const int* in_sizes, int n_in,
                              void* d_out, int out_size, void* d_ws, size_t ws_size,
                              hipStream_t stream)
{
    const float* x      = (const float*)d_in[0];
    const int*   labels = (const int*)d_in[1];
    const float* lw1    = (const float*)d_in[2];
    const float* lb1    = (const float*)d_in[3];
    const float* lw2    = (const float*)d_in[4];
    const float* lb2    = (const float*)d_in[5];
    const float* lw3    = (const float*)d_in[6];
    const float* lb3    = (const float*)d_in[7];
    const float* basek  = (const float*)d_in[8];
    const float* bw1    = (const float*)d_in[9];
    const float* bb1    = (const float*)d_in[10];
    const float* bw2    = (const float*)d_in[11];
    const float* bb2    = (const float*)d_in[12];
    float* out = (float*)d_out;

    char* ws = (char*)d_ws;
    unsigned short* lists   = (unsigned short*)(ws);
    int*            counts  = (int*)(ws + 2097152);
    float*          biasrows= (float*)(ws + 2098176);
    unsigned short* basekF  = (unsigned short*)(ws + 2163712);
    unsigned short* slotmap = (unsigned short*)(ws + 2753536);
    unsigned short* xcl     = (unsigned short*)(ws + 2884608);
    unsigned short* outc    = (unsigned short*)(ws + 11805696);
    unsigned short* wt      = (unsigned short*)(ws + 20194304);
    int*            bars    = (int*)out;

    hipMemsetAsync(out, 0, 8, stream);
    k_fused<<<NBLK, 1024, 149760, stream>>>(x, labels, lw1, lb1, lw2, lb2, lw3, lb3,
                                            basek, bw1, bb1, bw2, bb2,
                                            xcl, basekF, lists, slotmap, counts,
                                            biasrows, wt, outc, bars);
    k_scatter<<<1024, 256, 0, stream>>>(labels, slotmap, counts, outc, out);
}

// Round 7
// 130.338 us; speedup vs baseline: 3.4267x; 3.4267x over previous
//
#include <hip/hip_runtime.h>
#include <stdint.h>
#include <stddef.h>

// Problem constants
#define NB   16
#define NC   64
#define NH   64
#define NW   64
#define KC   16
#define NOUT 64
#define NRANK 8
#define NMLP 32
#define NF   576      // C*3*3
#define NPIX 4096     // H*W
#define XH   66       // halo height/width for channel-last copy
#define OROWS 8192    // interleaved outc rows per image (row = slot*16 + k)

typedef short s16x8 __attribute__((ext_vector_type(8)));
typedef short s16x4 __attribute__((ext_vector_type(4)));
typedef float f32x4 __attribute__((ext_vector_type(4)));

__device__ __forceinline__ unsigned short f2bf(float x) {
    union { float f; uint32_t u; } v; v.f = x;
    uint32_t r = v.u + 0x7FFFu + ((v.u >> 16) & 1u);   // RTNE
    return (unsigned short)(r >> 16);
}
__device__ __forceinline__ float bf2f(unsigned short u) {
    union { uint32_t u; float f; } v; v.u = ((uint32_t)u) << 16;
    return v.f;
}

// ---------------------------------------------------------------------------
// k_prep_all (R0 exact): blocks [0,1056): xcl; [1056,1128): basekF.
// ---------------------------------------------------------------------------
extern "C" __global__ __launch_bounds__(256)
void k_prep_all(const float* __restrict__ x, const float* __restrict__ basek,
                unsigned short* __restrict__ xcl, unsigned short* __restrict__ basekF)
{
    __shared__ float tile[64 * 65];
    const int blk0 = blockIdx.x;
    const int tid = threadIdx.x;
    if (blk0 < XH * 16) {
        const int b = blk0 & 15, yy = blk0 >> 4;
        unsigned short* dst = xcl + ((size_t)(b * XH + yy) * XH) * 64;
        if (yy == 0 || yy == XH - 1) {
            for (int e = tid; e < XH * 64; e += 256) dst[e] = 0;
            return;
        }
        const int y = yy - 1;
        const float* src = x + (size_t)b * NC * (NH * NW) + y * NW;
        #pragma unroll
        for (int rr = 0; rr < 16; ++rr) {
            int c = rr * 4 + (tid >> 6);
            int xx = tid & 63;
            tile[c * 65 + xx] = src[(size_t)c * (NH * NW) + xx];
        }
        __syncthreads();
        for (int ee = tid; ee < 528; ee += 256) {
            int xx = ee >> 3;
            int c0 = (ee & 7) * 8;
            s16x8 v;
            #pragma unroll
            for (int j = 0; j < 8; ++j) {
                float f = (xx == 0 || xx == XH - 1) ? 0.f : tile[(c0 + j) * 65 + (xx - 1)];
                v[j] = (short)f2bf(f);
            }
            *reinterpret_cast<s16x8*>(dst + ee * 8) = v;
        }
    } else {
        const int blk = blk0 - XH * 16;    // ks*4 + wv
        const int ks = blk >> 2, wv = blk & 3;
        unsigned short outv[16];
        #pragma unroll
        for (int i = 0; i < 16; ++i) {
            int e = tid * 16 + i;          // e = r*512 + lane*8 + j
            int r = e >> 9;
            int lane = (e >> 3) & 63;
            int j = e & 7;
            int col = wv * 16 + (lane & 15);
            int fp = (lane >> 4) * 8 + ks * 32 + j;
            int tap = fp >> 6, c = fp & 63;
            outv[i] = f2bf(basek[((size_t)r * NF + c * 9 + tap) * NOUT + col]);
        }
        unsigned short* dst = basekF + (size_t)blk * 4096 + tid * 16;
        #pragma unroll
        for (int i = 0; i < 16; ++i) dst[i] = outv[i];
    }
}

// ---------------------------------------------------------------------------
// k_cm (R6): fused centers+main, one block per (b,k), 1024 threads.
// No cross-block deps: outc row index is INTERLEAVED (slot*16 + k), so no
// prefix/counts; list stays in LDS; W-expansion goes to LDS (R13-proven);
// GEMM phase is R12's albuf structure as 4 sub-groups (R5 phase-C code).
// Eliminated from global: wt (18.9 MB), lists, counts, biasrows.
// Dynamic LDS 157,952 B:
//   list   @ 0       (8192)   live all phases
//   wcnt   @ 8192    (64)     compaction only
//   wsum   @ 8256    (36864)  gather
//   cbuf   @ 45120   (2304)   centers
//   p1     @ 47424   (1024)   MLP
//   pb     @ 48448   (1024)
//   h1     @ 49472   (128)
//   h2     @ 49600   (128)
//   hb     @ 49728   (128)
//   lrs    @ 49856   (32)
//   Wl     @ 51200   (73728)  W-expansion (dead after bfr load)
//   albuf  @ 8192 + sg*37376  (4x37376, ends 157696) GEMM stage
//   biasl  @ 157696  (256)    persistent bias
// ---------------------------------------------------------------------------
extern "C" __global__ __launch_bounds__(1024, 1)
void k_cm(const unsigned short* __restrict__ xcl, const int* __restrict__ labels,
          const float* __restrict__ lw1, const float* __restrict__ lb1,
          const float* __restrict__ lw2, const float* __restrict__ lb2,
          const float* __restrict__ lw3, const float* __restrict__ lb3,
          const float* __restrict__ bw1, const float* __restrict__ bb1,
          const float* __restrict__ bw2, const float* __restrict__ bb2,
          const unsigned short* __restrict__ basekF,
          unsigned short* __restrict__ slotmap, unsigned short* __restrict__ outc)
{
    extern __shared__ __align__(16) char smem[];
    unsigned short* list = (unsigned short*)smem;
    int*   wcnt  = (int*)(smem + 8192);
    float* wsum  = (float*)(smem + 8256);
    float* cbuf  = (float*)(smem + 45120);
    float* p1    = (float*)(smem + 47424);
    float* pb    = (float*)(smem + 48448);
    float* h1    = (float*)(smem + 49472);
    float* h2    = (float*)(smem + 49600);
    float* hb    = (float*)(smem + 49728);
    float* lrs   = (float*)(smem + 49856);
    unsigned short* Wl = (unsigned short*)(smem + 51200);
    float* biasl = (float*)(smem + 157696);

    const int bk = blockIdx.x;
    const int b = bk & 15, k = bk >> 4;
    const int tid = threadIdx.x;
    const int lane = tid & 63, wv = tid >> 6;    // wv 0..15
    const int st = tid & 255, sg = tid >> 8;     // 4 sub-groups of 256
    const int* lab = labels + b * NPIX;

    // ---- order-preserving compaction (4 iterations)
    int total = 0;
    #pragma unroll 1
    for (int base = 0; base < NPIX; base += 1024) {
        int n = base + tid;
        bool pred = (lab[n] == k);
        unsigned long long m = __ballot(pred);
        if (lane == 0) wcnt[wv] = __popcll(m);
        int pre = __popcll(m & ((1ull << lane) - 1ull));
        __syncthreads();
        int wbase = total;
        for (int i = 0; i < wv; ++i) wbase += wcnt[i];
        int nt = total;
        for (int i = 0; i < 16; ++i) nt += wcnt[i];
        if (pred) {
            int slot = wbase + pre;
            list[slot] = (unsigned short)n;
            slotmap[b * NPIX + n] = (unsigned short)slot;
        }
        total = nt;
        __syncthreads();
    }
    const int cnt = total;

    // ---- gather: wave wv handles pixels i = wv, wv+16, ...; lane = channel
    float s00 = 0.f, s01 = 0.f, s02 = 0.f,
          s10 = 0.f, s11 = 0.f, s12 = 0.f,
          s20 = 0.f, s21 = 0.f, s22 = 0.f;
    const unsigned short* xb0 = xcl + (size_t)b * (XH * XH * 64) + lane;
    #pragma unroll 2
    for (int i = wv; i < cnt; i += 16) {
        int n = list[i];
        const unsigned short* p0 = xb0 + (((n >> 6) * XH) + (n & 63)) * 64;
        s00 += bf2f(p0[0]);
        s01 += bf2f(p0[64]);
        s02 += bf2f(p0[128]);
        const unsigned short* prow1 = p0 + XH * 64;
        s10 += bf2f(prow1[0]);
        s11 += bf2f(prow1[64]);
        s12 += bf2f(prow1[128]);
        const unsigned short* prow2 = p0 + 2 * XH * 64;
        s20 += bf2f(prow2[0]);
        s21 += bf2f(prow2[64]);
        s22 += bf2f(prow2[128]);
    }
    {
        float* wrow = wsum + wv * 576 + lane;
        wrow[0 * 64] = s00; wrow[1 * 64] = s01; wrow[2 * 64] = s02;
        wrow[3 * 64] = s10; wrow[4 * 64] = s11; wrow[5 * 64] = s12;
        wrow[6 * 64] = s20; wrow[7 * 64] = s21; wrow[8 * 64] = s22;
    }
    __syncthreads();

    // ---- reduce 16 waves -> centers (feature order c*9+tap)
    const float inv = 1.f / ((float)cnt + 1e-6f);
    if (tid < NF) {
        int tap = tid >> 6, c = tid & 63;
        float s = 0.f;
        #pragma unroll
        for (int w = 0; w < 16; ++w) s += wsum[w * 576 + tap * 64 + c];
        cbuf[c * 9 + tap] = s * inv;
    }
    __syncthreads();

    // ---- fused MLPs
    if (tid < 256) {
        const int j = tid & 31, ch = tid >> 5;       // 8 chunks x 72 feats
        float a1 = 0.f, a2 = 0.f;
        for (int i = 0; i < 72; ++i) {
            int f = ch * 72 + i;
            float cv = cbuf[f];
            a1 += cv * lw1[f * NMLP + j];
            a2 += cv * bw1[f * NMLP + j];
        }
        p1[ch * NMLP + j] = a1; pb[ch * NMLP + j] = a2;
    }
    __syncthreads();
    if (tid < NMLP) {
        float a = lb1[tid];
        for (int i = 0; i < 8; ++i) a += p1[i * NMLP + tid];
        h1[tid] = fmaxf(a, 0.f);
    } else if (tid < 2 * NMLP) {
        int j = tid - NMLP;
        float a = bb1[j];
        for (int i = 0; i < 8; ++i) a += pb[i * NMLP + j];
        hb[j] = fmaxf(a, 0.f);
    }
    __syncthreads();
    if (tid < NMLP) {
        float a = lb2[tid];
        for (int i = 0; i < NMLP; ++i) a += h1[i] * lw2[i * NMLP + tid];
        h2[tid] = fmaxf(a, 0.f);
    } else if (tid >= 64 && tid < 128) {
        int o = tid - 64;
        float a = bb2[o];
        for (int i = 0; i < NMLP; ++i) a += hb[i] * bw2[i * NOUT + o];
        biasl[o] = a;                           // LDS, not global
    }
    __syncthreads();
    if (tid < NRANK) {
        float a = lb3[tid];
        for (int i = 0; i < NMLP; ++i) a += h2[i] * lw3[i * NRANK + tid];
        lrs[tid] = a;
    }
    __syncthreads();

    // ---- W-expansion into LDS Wl (R13-proven math, identical rounding)
    {
        float l8[NRANK];
        #pragma unroll
        for (int r = 0; r < NRANK; ++r) l8[r] = lrs[r];
        #pragma unroll 2
        for (int q = 0; q < 5; ++q) {
            int m = q * 1024 + tid;            // 0..4607 valid
            if (m < 4608) {
                int ks = m >> 8, t = m & 255;
                const unsigned short* src = basekF
                    + ((size_t)(ks * 4 + (t >> 6)) * 8) * 512 + (t & 63) * 8;
                float w[8] = {0.f, 0.f, 0.f, 0.f, 0.f, 0.f, 0.f, 0.f};
                #pragma unroll
                for (int r = 0; r < NRANK; ++r) {
                    s16x8 bv = *reinterpret_cast<const s16x8*>(src + r * 512);
                    #pragma unroll
                    for (int j = 0; j < 8; ++j)
                        w[j] += l8[r] * bf2f((unsigned short)bv[j]);
                }
                s16x8 f;
                #pragma unroll
                for (int j = 0; j < 8; ++j) f[j] = (short)f2bf(w[j]);
                *reinterpret_cast<s16x8*>(Wl + m * 8) = f;
            }
        }
    }
    __syncthreads();

    // ---- load B-fragments from Wl into registers, then free Wl for albufs
    s16x8 bfr[18];
    #pragma unroll
    for (int ks = 0; ks < 18; ++ks)
        bfr[ks] = *reinterpret_cast<const s16x8*>(Wl + ks * 2048 + st * 8);
    __syncthreads();

    // ---- main GEMM (R12 structure, 4 sub-groups; output rows interleaved)
    {
        const int wv4 = (tid >> 6) & 3;
        const int quad = lane >> 4, l16 = lane & 15;
        unsigned short* albuf = (unsigned short*)(smem + 8192 + sg * 37376);
        const int col = wv4 * 16 + l16;
        const float bb = biasl[col];
        const unsigned short* xb = xcl + (size_t)b * (XH * XH * 64);
        const int p = st >> 3, part = st & 7;
        const int ntile = (cnt + 31) >> 5;
        const int niter = (ntile + 3) >> 2;
        unsigned short* ob = outc + (size_t)b * (OROWS * 64);

        #pragma unroll 1
        for (int it = 0; it < niter; ++it) {
            const int t = it * 4 + sg;
            const bool live = (t < ntile);
            if (live) {
                int slot = (t << 5) + p;
                int n = (slot < cnt) ? (int)list[slot] : 0;
                const unsigned short* xrow =
                    xb + (((n >> 6) * XH) + (n & 63)) * 64 + part * 8;
                unsigned short* arow = albuf + p * 584 + part * 8;
                #pragma unroll
                for (int tap = 0; tap < 9; ++tap) {
                    int dy = tap / 3, dx = tap - dy * 3;
                    *reinterpret_cast<s16x8*>(arow + tap * 64) =
                        *reinterpret_cast<const s16x8*>(xrow + (dy * XH + dx) * 64);
                }
            }
            __syncthreads();
            if (live) {
                f32x4 acc0 = {0.f, 0.f, 0.f, 0.f}, acc1 = {0.f, 0.f, 0.f, 0.f};
                const unsigned short* ar0 = albuf + l16 * 584 + quad * 8;
                const unsigned short* ar1 = ar0 + 16 * 584;
                #pragma unroll
                for (int ks = 0; ks < 18; ++ks) {
                    s16x8 a0 = *reinterpret_cast<const s16x8*>(ar0 + ks * 32);
                    s16x8 a1 = *reinterpret_cast<const s16x8*>(ar1 + ks * 32);
                    acc0 = __builtin_amdgcn_mfma_f32_16x16x32_bf16(a0, bfr[ks], acc0, 0, 0, 0);
                    acc1 = __builtin_amdgcn_mfma_f32_16x16x32_bf16(a1, bfr[ks], acc1, 0, 0, 0);
                }
                #pragma unroll
                for (int r = 0; r < 4; ++r) {
                    int s0 = (t << 5) + quad * 4 + r;
                    if (s0 < cnt)
                        ob[(size_t)(s0 * 16 + k) * 64 + col] = f2bf(acc0[r] + bb);
                    int s1 = s0 + 16;
                    if (s1 < cnt)
                        ob[(size_t)(s1 * 16 + k) * 64 + col] = f2bf(acc1[r] + bb);
                }
            }
            __syncthreads();
        }
    }
}

// ---------------------------------------------------------------------------
// k_scatter (R6): grid 1024. Interleaved outc: row = slotmap[n]*16 + lab[n],
// no prefix/counts needed. 16B gathers, LDS transpose (rows padded to 20
// u16), coalesced f32 stores.
// ---------------------------------------------------------------------------
extern "C" __global__ __launch_bounds__(256)
void k_scatter(const int* __restrict__ labels, const unsigned short* __restrict__ slotmap,
               const unsigned short* __restrict__ outc, float* __restrict__ out)
{
    const int blk = blockIdx.x;
    const int b = blk & 15, chunk = (blk >> 4) & 15, q = blk >> 8;
    const int tid = threadIdx.x;
    __shared__ int sptr[256];
    __shared__ unsigned short tt[256 * 20];     // 10 KB
    const int n0 = chunk * 256;
    {
        int n = n0 + tid;
        sptr[tid] = (int)slotmap[b * NPIX + n] * 16 + labels[b * NPIX + n];
    }
    __syncthreads();
    #pragma unroll
    for (int e0 = 0; e0 < 2; ++e0) {
        int e = e0 * 256 + tid;
        int pix = e >> 1, part = e & 1;
        s16x8 vv = *reinterpret_cast<const s16x8*>(
            outc + ((size_t)b * (OROWS * 64)) + (size_t)sptr[pix] * 64 + q * 16 + part * 8);
        s16x4 lo = {vv[0], vv[1], vv[2], vv[3]};
        s16x4 hi = {vv[4], vv[5], vv[6], vv[7]};
        *reinterpret_cast<s16x4*>(tt + pix * 20 + part * 8) = lo;
        *reinterpret_cast<s16x4*>(tt + pix * 20 + part * 8 + 4) = hi;
    }
    __syncthreads();
    float* ob = out + ((size_t)(b * NOUT + q * 16)) * NPIX + n0;
    #pragma unroll
    for (int oo = 0; oo < 16; ++oo)
        ob[(size_t)oo * NPIX + tid] = bf2f(tt[tid * 20 + oo]);
}

// ---------------------------------------------------------------------------
// Workspace layout (total used 26,419,200 of 39,068,672 B):
//   basekF  @ 0        : 589,824
//   slotmap @ 589824   : 131,072
//   xcl     @ 720896   : 8,921,088
//   outc    @ 9641984  : 16,777,216   (16 images x 8192 interleaved rows x 64)
// Removed vs R0: wt, lists, counts, biasrows.
// ---------------------------------------------------------------------------
extern "C" void kernel_launch(void* const* d_in, const int* in_sizes, int n_in,
                              void* d_out, int out_size, void* d_ws, size_t ws_size,
                              hipStream_t stream)
{
    const float* x      = (const float*)d_in[0];
    const int*   labels = (const int*)d_in[1];
    const float* lw1    = (const float*)d_in[2];
    const float* lb1    = (const float*)d_in[3];
    const float* lw2    = (const float*)d_in[4];
    const float* lb2    = (const float*)d_in[5];
    const float* lw3    = (const float*)d_in[6];
    const float* lb3    = (const float*)d_in[7];
    const float* basek  = (const float*)d_in[8];
    const float* bw1    = (const float*)d_in[9];
    const float* bb1    = (const float*)d_in[10];
    const float* bw2    = (const float*)d_in[11];
    const float* bb2    = (const float*)d_in[12];
    float* out = (float*)d_out;

    char* ws = (char*)d_ws;
    unsigned short* basekF  = (unsigned short*)(ws);
    unsigned short* slotmap = (unsigned short*)(ws + 589824);
    unsigned short* xcl     = (unsigned short*)(ws + 720896);
    unsigned short* outc    = (unsigned short*)(ws + 9641984);

    k_prep_all<<<XH * 16 + 72, 256, 0, stream>>>(x, basek, xcl, basekF);
    k_cm<<<256, 1024, 157952, stream>>>(xcl, labels, lw1, lb1, lw2, lb2, lw3, lb3,
                                        bw1, bb1, bw2, bb2, basekF, slotmap, outc);
    k_scatter<<<1024, 256, 0, stream>>>(labels, slotmap, outc, out);
}

// Round 8
// 124.364 us; speedup vs baseline: 3.5913x; 1.0480x over previous
//
#include <hip/hip_runtime.h>
#include <stdint.h>
#include <stddef.h>

// Problem constants
#define NB   16
#define NC   64
#define NH   64
#define NW   64
#define KC   16
#define NOUT 64
#define NRANK 8
#define NMLP 32
#define NF   576      // C*3*3
#define NPIX 4096     // H*W
#define XH   66       // halo height/width for channel-last copy
#define OROWS 8192    // interleaved outc rows per image (row = slot*16 + k)

typedef short s16x8 __attribute__((ext_vector_type(8)));
typedef short s16x4 __attribute__((ext_vector_type(4)));
typedef float f32x4 __attribute__((ext_vector_type(4)));

__device__ __forceinline__ unsigned short f2bf(float x) {
    union { float f; uint32_t u; } v; v.f = x;
    uint32_t r = v.u + 0x7FFFu + ((v.u >> 16) & 1u);   // RTNE
    return (unsigned short)(r >> 16);
}
__device__ __forceinline__ float bf2f(unsigned short u) {
    union { uint32_t u; float f; } v; v.u = ((uint32_t)u) << 16;
    return v.f;
}

// ---------------------------------------------------------------------------
// k_prep_all (R0 exact): blocks [0,1056): xcl; [1056,1128): basekF.
// ---------------------------------------------------------------------------
extern "C" __global__ __launch_bounds__(256)
void k_prep_all(const float* __restrict__ x, const float* __restrict__ basek,
                unsigned short* __restrict__ xcl, unsigned short* __restrict__ basekF)
{
    __shared__ float tile[64 * 65];
    const int blk0 = blockIdx.x;
    const int tid = threadIdx.x;
    if (blk0 < XH * 16) {
        const int b = blk0 & 15, yy = blk0 >> 4;
        unsigned short* dst = xcl + ((size_t)(b * XH + yy) * XH) * 64;
        if (yy == 0 || yy == XH - 1) {
            for (int e = tid; e < XH * 64; e += 256) dst[e] = 0;
            return;
        }
        const int y = yy - 1;
        const float* src = x + (size_t)b * NC * (NH * NW) + y * NW;
        #pragma unroll
        for (int rr = 0; rr < 16; ++rr) {
            int c = rr * 4 + (tid >> 6);
            int xx = tid & 63;
            tile[c * 65 + xx] = src[(size_t)c * (NH * NW) + xx];
        }
        __syncthreads();
        for (int ee = tid; ee < 528; ee += 256) {
            int xx = ee >> 3;
            int c0 = (ee & 7) * 8;
            s16x8 v;
            #pragma unroll
            for (int j = 0; j < 8; ++j) {
                float f = (xx == 0 || xx == XH - 1) ? 0.f : tile[(c0 + j) * 65 + (xx - 1)];
                v[j] = (short)f2bf(f);
            }
            *reinterpret_cast<s16x8*>(dst + ee * 8) = v;
        }
    } else {
        const int blk = blk0 - XH * 16;    // ks*4 + wv
        const int ks = blk >> 2, wv = blk & 3;
        unsigned short outv[16];
        #pragma unroll
        for (int i = 0; i < 16; ++i) {
            int e = tid * 16 + i;          // e = r*512 + lane*8 + j
            int r = e >> 9;
            int lane = (e >> 3) & 63;
            int j = e & 7;
            int col = wv * 16 + (lane & 15);
            int fp = (lane >> 4) * 8 + ks * 32 + j;
            int tap = fp >> 6, c = fp & 63;
            outv[i] = f2bf(basek[((size_t)r * NF + c * 9 + tap) * NOUT + col]);
        }
        unsigned short* dst = basekF + (size_t)blk * 4096 + tid * 16;
        #pragma unroll
        for (int i = 0; i < 16; ++i) dst[i] = outv[i];
    }
}

// ---------------------------------------------------------------------------
// k_cm (R8): fused centers+main, one block per (b,k), 1024 threads.
// R8 changes vs R7:
//  - UNORDERED single-atomic compaction (slot order need not follow pixel
//    order: gather is an order-insensitive sum; GEMM/scatter only need
//    list<->slotmap consistency). 2 barriers instead of 8, no serial prefix.
//  - gather unroll 2 -> 4 (scalar accumulators, spill-safe).
// Dynamic LDS 157,952 B (layout unchanged from R7).
// ---------------------------------------------------------------------------
extern "C" __global__ __launch_bounds__(1024, 1)
void k_cm(const unsigned short* __restrict__ xcl, const int* __restrict__ labels,
          const float* __restrict__ lw1, const float* __restrict__ lb1,
          const float* __restrict__ lw2, const float* __restrict__ lb2,
          const float* __restrict__ lw3, const float* __restrict__ lb3,
          const float* __restrict__ bw1, const float* __restrict__ bb1,
          const float* __restrict__ bw2, const float* __restrict__ bb2,
          const unsigned short* __restrict__ basekF,
          unsigned short* __restrict__ slotmap, unsigned short* __restrict__ outc)
{
    extern __shared__ __align__(16) char smem[];
    unsigned short* list = (unsigned short*)smem;
    int*   wcnt  = (int*)(smem + 8192);
    float* wsum  = (float*)(smem + 8256);
    float* cbuf  = (float*)(smem + 45120);
    float* p1    = (float*)(smem + 47424);
    float* pb    = (float*)(smem + 48448);
    float* h1    = (float*)(smem + 49472);
    float* h2    = (float*)(smem + 49600);
    float* hb    = (float*)(smem + 49728);
    float* lrs   = (float*)(smem + 49856);
    unsigned short* Wl = (unsigned short*)(smem + 51200);
    float* biasl = (float*)(smem + 157696);

    const int bk = blockIdx.x;
    const int b = bk & 15, k = bk >> 4;
    const int tid = threadIdx.x;
    const int lane = tid & 63, wv = tid >> 6;    // wv 0..15
    const int st = tid & 255, sg = tid >> 8;     // 4 sub-groups of 256
    const int* lab = labels + b * NPIX;

    // ---- unordered single-atomic compaction (R8)
    if (tid == 0) wcnt[0] = 0;
    __syncthreads();
    {
        const int n0 = tid, n1 = 1024 + tid, n2 = 2048 + tid, n3 = 3072 + tid;
        const int l0 = lab[n0], l1 = lab[n1], l2 = lab[n2], l3 = lab[n3];
        const bool q0 = (l0 == k), q1 = (l1 == k), q2 = (l2 == k), q3 = (l3 == k);
        const unsigned long long m0 = __ballot(q0), m1 = __ballot(q1),
                                 m2 = __ballot(q2), m3 = __ballot(q3);
        const int c0 = __popcll(m0), c1 = __popcll(m1),
                  c2 = __popcll(m2), c3 = __popcll(m3);
        int base = 0;
        if (lane == 0)
            base = __hip_atomic_fetch_add(&wcnt[0], c0 + c1 + c2 + c3,
                                          __ATOMIC_RELAXED, __HIP_MEMORY_SCOPE_WORKGROUP);
        base = __shfl(base, 0);
        const unsigned long long lt = (1ull << lane) - 1ull;
        if (q0) { int s = base + __popcll(m0 & lt);
                  list[s] = (unsigned short)n0; slotmap[b * NPIX + n0] = (unsigned short)s; }
        base += c0;
        if (q1) { int s = base + __popcll(m1 & lt);
                  list[s] = (unsigned short)n1; slotmap[b * NPIX + n1] = (unsigned short)s; }
        base += c1;
        if (q2) { int s = base + __popcll(m2 & lt);
                  list[s] = (unsigned short)n2; slotmap[b * NPIX + n2] = (unsigned short)s; }
        base += c2;
        if (q3) { int s = base + __popcll(m3 & lt);
                  list[s] = (unsigned short)n3; slotmap[b * NPIX + n3] = (unsigned short)s; }
    }
    __syncthreads();
    const int cnt = wcnt[0];

    // ---- gather: wave wv handles pixels i = wv, wv+16, ...; lane = channel
    float s00 = 0.f, s01 = 0.f, s02 = 0.f,
          s10 = 0.f, s11 = 0.f, s12 = 0.f,
          s20 = 0.f, s21 = 0.f, s22 = 0.f;
    const unsigned short* xb0 = xcl + (size_t)b * (XH * XH * 64) + lane;
    #pragma unroll 4
    for (int i = wv; i < cnt; i += 16) {
        int n = list[i];
        const unsigned short* p0 = xb0 + (((n >> 6) * XH) + (n & 63)) * 64;
        s00 += bf2f(p0[0]);
        s01 += bf2f(p0[64]);
        s02 += bf2f(p0[128]);
        const unsigned short* prow1 = p0 + XH * 64;
        s10 += bf2f(prow1[0]);
        s11 += bf2f(prow1[64]);
        s12 += bf2f(prow1[128]);
        const unsigned short* prow2 = p0 + 2 * XH * 64;
        s20 += bf2f(prow2[0]);
        s21 += bf2f(prow2[64]);
        s22 += bf2f(prow2[128]);
    }
    {
        float* wrow = wsum + wv * 576 + lane;
        wrow[0 * 64] = s00; wrow[1 * 64] = s01; wrow[2 * 64] = s02;
        wrow[3 * 64] = s10; wrow[4 * 64] = s11; wrow[5 * 64] = s12;
        wrow[6 * 64] = s20; wrow[7 * 64] = s21; wrow[8 * 64] = s22;
    }
    __syncthreads();

    // ---- reduce 16 waves -> centers (feature order c*9+tap)
    const float inv = 1.f / ((float)cnt + 1e-6f);
    if (tid < NF) {
        int tap = tid >> 6, c = tid & 63;
        float s = 0.f;
        #pragma unroll
        for (int w = 0; w < 16; ++w) s += wsum[w * 576 + tap * 64 + c];
        cbuf[c * 9 + tap] = s * inv;
    }
    __syncthreads();

    // ---- fused MLPs
    if (tid < 256) {
        const int j = tid & 31, ch = tid >> 5;       // 8 chunks x 72 feats
        float a1 = 0.f, a2 = 0.f;
        for (int i = 0; i < 72; ++i) {
            int f = ch * 72 + i;
            float cv = cbuf[f];
            a1 += cv * lw1[f * NMLP + j];
            a2 += cv * bw1[f * NMLP + j];
        }
        p1[ch * NMLP + j] = a1; pb[ch * NMLP + j] = a2;
    }
    __syncthreads();
    if (tid < NMLP) {
        float a = lb1[tid];
        for (int i = 0; i < 8; ++i) a += p1[i * NMLP + tid];
        h1[tid] = fmaxf(a, 0.f);
    } else if (tid < 2 * NMLP) {
        int j = tid - NMLP;
        float a = bb1[j];
        for (int i = 0; i < 8; ++i) a += pb[i * NMLP + j];
        hb[j] = fmaxf(a, 0.f);
    }
    __syncthreads();
    if (tid < NMLP) {
        float a = lb2[tid];
        for (int i = 0; i < NMLP; ++i) a += h1[i] * lw2[i * NMLP + tid];
        h2[tid] = fmaxf(a, 0.f);
    } else if (tid >= 64 && tid < 128) {
        int o = tid - 64;
        float a = bb2[o];
        for (int i = 0; i < NMLP; ++i) a += hb[i] * bw2[i * NOUT + o];
        biasl[o] = a;                           // LDS, not global
    }
    __syncthreads();
    if (tid < NRANK) {
        float a = lb3[tid];
        for (int i = 0; i < NMLP; ++i) a += h2[i] * lw3[i * NRANK + tid];
        lrs[tid] = a;
    }
    __syncthreads();

    // ---- W-expansion into LDS Wl (R13-proven math, identical rounding)
    {
        float l8[NRANK];
        #pragma unroll
        for (int r = 0; r < NRANK; ++r) l8[r] = lrs[r];
        #pragma unroll 2
        for (int q = 0; q < 5; ++q) {
            int m = q * 1024 + tid;            // 0..4607 valid
            if (m < 4608) {
                int ks = m >> 8, t = m & 255;
                const unsigned short* src = basekF
                    + ((size_t)(ks * 4 + (t >> 6)) * 8) * 512 + (t & 63) * 8;
                float w[8] = {0.f, 0.f, 0.f, 0.f, 0.f, 0.f, 0.f, 0.f};
                #pragma unroll
                for (int r = 0; r < NRANK; ++r) {
                    s16x8 bv = *reinterpret_cast<const s16x8*>(src + r * 512);
                    #pragma unroll
                    for (int j = 0; j < 8; ++j)
                        w[j] += l8[r] * bf2f((unsigned short)bv[j]);
                }
                s16x8 f;
                #pragma unroll
                for (int j = 0; j < 8; ++j) f[j] = (short)f2bf(w[j]);
                *reinterpret_cast<s16x8*>(Wl + m * 8) = f;
            }
        }
    }
    __syncthreads();

    // ---- load B-fragments from Wl into registers, then free Wl for albufs
    s16x8 bfr[18];
    #pragma unroll
    for (int ks = 0; ks < 18; ++ks)
        bfr[ks] = *reinterpret_cast<const s16x8*>(Wl + ks * 2048 + st * 8);
    __syncthreads();

    // ---- main GEMM (R12 structure, 4 sub-groups; output rows interleaved)
    {
        const int wv4 = (tid >> 6) & 3;
        const int quad = lane >> 4, l16 = lane & 15;
        unsigned short* albuf = (unsigned short*)(smem + 8192 + sg * 37376);
        const int col = wv4 * 16 + l16;
        const float bb = biasl[col];
        const unsigned short* xb = xcl + (size_t)b * (XH * XH * 64);
        const int p = st >> 3, part = st & 7;
        const int ntile = (cnt + 31) >> 5;
        const int niter = (ntile + 3) >> 2;
        unsigned short* ob = outc + (size_t)b * (OROWS * 64);

        #pragma unroll 1
        for (int it = 0; it < niter; ++it) {
            const int t = it * 4 + sg;
            const bool live = (t < ntile);
            if (live) {
                int slot = (t << 5) + p;
                int n = (slot < cnt) ? (int)list[slot] : 0;
                const unsigned short* xrow =
                    xb + (((n >> 6) * XH) + (n & 63)) * 64 + part * 8;
                unsigned short* arow = albuf + p * 584 + part * 8;
                #pragma unroll
                for (int tap = 0; tap < 9; ++tap) {
                    int dy = tap / 3, dx = tap - dy * 3;
                    *reinterpret_cast<s16x8*>(arow + tap * 64) =
                        *reinterpret_cast<const s16x8*>(xrow + (dy * XH + dx) * 64);
                }
            }
            __syncthreads();
            if (live) {
                f32x4 acc0 = {0.f, 0.f, 0.f, 0.f}, acc1 = {0.f, 0.f, 0.f, 0.f};
                const unsigned short* ar0 = albuf + l16 * 584 + quad * 8;
                const unsigned short* ar1 = ar0 + 16 * 584;
                #pragma unroll
                for (int ks = 0; ks < 18; ++ks) {
                    s16x8 a0 = *reinterpret_cast<const s16x8*>(ar0 + ks * 32);
                    s16x8 a1 = *reinterpret_cast<const s16x8*>(ar1 + ks * 32);
                    acc0 = __builtin_amdgcn_mfma_f32_16x16x32_bf16(a0, bfr[ks], acc0, 0, 0, 0);
                    acc1 = __builtin_amdgcn_mfma_f32_16x16x32_bf16(a1, bfr[ks], acc1, 0, 0, 0);
                }
                #pragma unroll
                for (int r = 0; r < 4; ++r) {
                    int s0 = (t << 5) + quad * 4 + r;
                    if (s0 < cnt)
                        ob[(size_t)(s0 * 16 + k) * 64 + col] = f2bf(acc0[r] + bb);
                    int s1 = s0 + 16;
                    if (s1 < cnt)
                        ob[(size_t)(s1 * 16 + k) * 64 + col] = f2bf(acc1[r] + bb);
                }
            }
            __syncthreads();
        }
    }
}

// ---------------------------------------------------------------------------
// k_scatter (R6): grid 1024. Interleaved outc: row = slotmap[n]*16 + lab[n],
// no prefix/counts needed. 16B gathers, LDS transpose (rows padded to 20
// u16), coalesced f32 stores.
// ---------------------------------------------------------------------------
extern "C" __global__ __launch_bounds__(256)
void k_scatter(const int* __restrict__ labels, const unsigned short* __restrict__ slotmap,
               const unsigned short* __restrict__ outc, float* __restrict__ out)
{
    const int blk = blockIdx.x;
    const int b = blk & 15, chunk = (blk >> 4) & 15, q = blk >> 8;
    const int tid = threadIdx.x;
    __shared__ int sptr[256];
    __shared__ unsigned short tt[256 * 20];     // 10 KB
    const int n0 = chunk * 256;
    {
        int n = n0 + tid;
        sptr[tid] = (int)slotmap[b * NPIX + n] * 16 + labels[b * NPIX + n];
    }
    __syncthreads();
    #pragma unroll
    for (int e0 = 0; e0 < 2; ++e0) {
        int e = e0 * 256 + tid;
        int pix = e >> 1, part = e & 1;
        s16x8 vv = *reinterpret_cast<const s16x8*>(
            outc + ((size_t)b * (OROWS * 64)) + (size_t)sptr[pix] * 64 + q * 16 + part * 8);
        s16x4 lo = {vv[0], vv[1], vv[2], vv[3]};
        s16x4 hi = {vv[4], vv[5], vv[6], vv[7]};
        *reinterpret_cast<s16x4*>(tt + pix * 20 + part * 8) = lo;
        *reinterpret_cast<s16x4*>(tt + pix * 20 + part * 8 + 4) = hi;
    }
    __syncthreads();
    float* ob = out + ((size_t)(b * NOUT + q * 16)) * NPIX + n0;
    #pragma unroll
    for (int oo = 0; oo < 16; ++oo)
        ob[(size_t)oo * NPIX + tid] = bf2f(tt[tid * 20 + oo]);
}

// ---------------------------------------------------------------------------
// Workspace layout (total used 26,419,200 of 39,068,672 B):
//   basekF  @ 0        : 589,824
//   slotmap @ 589824   : 131,072
//   xcl     @ 720896   : 8,921,088
//   outc    @ 9641984  : 16,777,216   (16 images x 8192 interleaved rows x 64)
// ---------------------------------------------------------------------------
extern "C" void kernel_launch(void* const* d_in, const int* in_sizes, int n_in,
                              void* d_out, int out_size, void* d_ws, size_t ws_size,
                              hipStream_t stream)
{
    const float* x      = (const float*)d_in[0];
    const int*   labels = (const int*)d_in[1];
    const float* lw1    = (const float*)d_in[2];
    const float* lb1    = (const float*)d_in[3];
    const float* lw2    = (const float*)d_in[4];
    const float* lb2    = (const float*)d_in[5];
    const float* lw3    = (const float*)d_in[6];
    const float* lb3    = (const float*)d_in[7];
    const float* basek  = (const float*)d_in[8];
    const float* bw1    = (const float*)d_in[9];
    const float* bb1    = (const float*)d_in[10];
    const float* bw2    = (const float*)d_in[11];
    const float* bb2    = (const float*)d_in[12];
    float* out = (float*)d_out;

    char* ws = (char*)d_ws;
    unsigned short* basekF  = (unsigned short*)(ws);
    unsigned short* slotmap = (unsigned short*)(ws + 589824);
    unsigned short* xcl     = (unsigned short*)(ws + 720896);
    unsigned short* outc    = (unsigned short*)(ws + 9641984);

    k_prep_all<<<XH * 16 + 72, 256, 0, stream>>>(x, basek, xcl, basekF);
    k_cm<<<256, 1024, 157952, stream>>>(xcl, labels, lw1, lb1, lw2, lb2, lw3, lb3,
                                        bw1, bb1, bw2, bb2, basekF, slotmap, outc);
    k_scatter<<<1024, 256, 0, stream>>>(labels, slotmap, outc, out);
}